// Round 11
// baseline (308.605 us; speedup 1.0000x reference)
//
#include <hip/hip_runtime.h>
#include <hip/hip_bf16.h>

#define EMB 128

typedef __attribute__((ext_vector_type(8))) short short8;   // 8 bf16 (4 VGPRs)
typedef __attribute__((ext_vector_type(4))) float floatx4;  // MFMA C/D

// 26 valid (ok, di, ol) message combos: deltas = {1,2,-1,-2}, ol = ok+delta in [0,8)
static constexpr int OKv[26] = {0,0,1,1,1,2,2,2,2,3,3,3,3,4,4,4,4,5,5,5,5,6,6,6,7,7};
static constexpr int DIv[26] = {0,1,0,1,2,0,1,2,3,0,1,2,3,0,1,2,3,0,1,2,3,0,2,3,2,3};
static constexpr int OLv[26] = {1,2,2,3,0,3,4,1,0,4,5,2,1,5,6,3,2,6,7,4,3,7,5,4,6,5};

__device__ __forceinline__ float4 ld4(const float* p) { return *(const float4*)p; }

// round-to-nearest-even bf16 bits of x, kept in the TOP 16 bits (low 16 zero)
__device__ __forceinline__ unsigned bf16_rne_hi(float x) {
  unsigned u = __float_as_uint(x);
  return (u + 0x7FFFu + ((u >> 16) & 1u)) & 0xFFFF0000u;
}
__device__ __forceinline__ float bf16hi_f(float x) {
  return __uint_as_float(bf16_rne_hi(x));
}
// HW packed cvt: a -> low 16, b -> high 16 (v_cvt_pk_bf16_f32 on gfx950)
__device__ __forceinline__ unsigned cvt_pk_bf16(float a, float b) {
  __hip_bfloat162 h = __float22bfloat162_rn(make_float2(a, b));
  unsigned r; __builtin_memcpy(&r, &h, 4); return r;
}

union FragU { unsigned u[4]; uint4 q; short8 v; };

// LOGICAL CHANNEL PERMUTATION (R11): MFMA C physical position (u, n=lane&15)
// carries logical channel L(u,n) = (u>>2)*64 + n*4 + (u&3). Wave wv computes
// u in {4wv..4wv+3} -> lane (wv,m16) holds 4 ADJACENT logical channels
// c0 = (wv*16+m16)*4 .. c0+3. Only wfrag bakes the permutation.

// Fused prep, grid 73 x 512 (structure validated R10-neutral; gap is harness):
//  b 0..31  : lin32 row b (4-way f-split + LDS reduce)
//  b 32..71 : w_conv -> B-fragment hi/lo pre-pack with permuted N
//  b 72     : out[g] = b_pred[0]
__global__ __launch_bounds__(512) void prep_kernel(
    const float* __restrict__ emb_x,
    const float* __restrict__ w_ti,
    const float* __restrict__ b_ti,
    const float* __restrict__ w_conv,
    const float* __restrict__ b_pred,
    float* __restrict__ lin32,
    uint4* __restrict__ wfrag,
    float* __restrict__ out) {
  const int b = blockIdx.x, tid = threadIdx.x;
  if (b < 32) {
    __shared__ float red[4][EMB];
    const int e = tid & 127, fh = tid >> 7;      // fh in [0,4)
    const float* xr = emb_x + b * EMB;
    float s = 0.f;
    #pragma unroll 8
    for (int f = fh * 32; f < fh * 32 + 32; ++f)
      s = fmaf(xr[f], w_ti[f * EMB + e], s);
    red[fh][e] = s;
    __syncthreads();
    if (fh == 0)
      lin32[b * EMB + e] =
          b_ti[e] + ((red[0][e] + red[1][e]) + (red[2][e] + red[3][e]));
  } else if (b < 72) {
    const int id   = (b - 32) * 512 + tid;   // 320 frags * 64 lanes = 20480
    const int lane = id & 63;
    const int f    = id >> 6;
    const int pass = f & 1;           // 0 = hi, 1 = lo
    const int u    = (f >> 1) & 7;    // N-tile (physical)
    const int t    = (f >> 4) & 3;    // K-tile
    const int l    = f >> 6;          // layer
    const int q    = lane >> 4, n = lane & 15;
    const int cN   = (u >> 2) * 64 + n * 4 + (u & 3);   // logical out channel
    unsigned w[4] = {0u, 0u, 0u, 0u};
    #pragma unroll
    for (int j = 0; j < 8; ++j) {
      const int kk = t * 32 + q * 8 + j;    // logical in channel (canonical)
      float val = w_conv[l * (EMB * EMB) + kk * EMB + cN];
      if (pass) val = val - bf16hi_f(val);
      const unsigned bb = bf16_rne_hi(val);
      w[j >> 1] |= (j & 1) ? bb : (bb >> 16);
    }
    wfrag[id] = make_uint4(w[0], w[1], w[2], w[3]);
  } else {
    if (tid < 64) out[tid] = b_pred[0];
  }
}

// Block = HALF a root node: 4 pairs = 32 M-rows, 128 threads (2 waves).
// M-row map row(pair,k) = (k>>2)*16 + pair*4 + (k&3): lane (m16,q2) owns
// pair q2, ALL 8 k, channels c0..c0+3 -> message pass is float4 lane-local.
// Per layer: 26 fma4 message pass (ea ld4 from global/L1) -> hi/lo pack as
// 2x8 b64 writes into A-frag LDS (stride-68 rows, 2-way-free) -> MFMA: wave
// wv does u=4wv..4wv+3 x 2 M-tiles x 4 kt x 3 split-terms (96) with B frags
// streamed from wfrag -> residual+relu in registers. 2 barriers/layer but
// scope = only 2 waves; LDS 17408 B -> ~6 indep blocks/CU. No occupancy
// attribute (R1/R6: forcing a budget -> 0.5-1.6 GB spills).
__global__ __launch_bounds__(128)
void i2gnn_mfma(
    const int* __restrict__ x,
    const int* __restrict__ edge_attr,
    const int* __restrict__ tuplefeat,
    const float* __restrict__ emb_x,
    const float* __restrict__ emb_tf,
    const float* __restrict__ emb_ea,
    const float* __restrict__ lin32,
    const float* __restrict__ b_conv,
    const float* __restrict__ w_pred,
    const uint4* __restrict__ wfrag,
    float* __restrict__ out)
{
  __shared__ __align__(16) unsigned fragA[2 * 32 * 68];  // 17408 B; lo at +2176

  const int tid = threadIdx.x;
  const int wv = tid >> 6, lane = tid & 63;
  const int m16 = lane & 15, q2 = lane >> 4;   // q2 = local pair
  const int c0 = (wv * 16 + m16) * 4;          // 4 adjacent logical channels

  const int b = blockIdx.x;
  const int i = b >> 1;                 // root node
  const int half = b & 1;               // which 4 of the 8 pairs
  const int ibase = i & ~63, io = i & 63;
  const int g = i >> 6;

  // 26 edge attrs (4 bits each) — function of i only
  unsigned pk[4] = {0u, 0u, 0u, 0u};
  #pragma unroll
  for (int m = 0; m < 26; ++m) {
    const int kg = ibase + ((io + OKv[m]) & 63);
    const unsigned a = (unsigned)edge_attr[(kg << 2) + DIv[m]];
    pk[m >> 3] |= a << ((m & 7) * 4);
  }

  // tupleinit: lane owns pair jj = half*4+q2, all 8 k, channels c0..c0+3
  const int jj = half * 4 + q2;
  const int jn = ibase + ((io + jj) & 63);
  const float4 xe = ld4(emb_x + x[i] * EMB + c0);
  const float4 lj = ld4(lin32 + x[jn] * EMB + c0);
  float4 X[8];
  const int t0 = (i * 8 + jj) * 8;
  #pragma unroll
  for (int k = 0; k < 8; ++k) {
    const int2 tf2 = *(const int2*)(tuplefeat + 2 * (t0 + k));
    const int row = (c0 < 64) ? tf2.x : tf2.y;   // 4 adjacent ch in same half
    const float4 tf = ld4(emb_tf + row * 64 + (c0 & 63));
    X[k] = make_float4(xe.x * lj.x * tf.x, xe.y * lj.y * tf.y,
                       xe.z * lj.z * tf.z, xe.w * lj.w * tf.w);
  }

  for (int l = 0; l < 5; ++l) {
    // ---- message pass: fully lane-local, float4 over 4 adjacent channels ----
    float4 acc[8];
    #pragma unroll
    for (int k = 0; k < 8; ++k) acc[k] = make_float4(0.f, 0.f, 0.f, 0.f);
    #pragma unroll
    for (int m = 0; m < 26; ++m) {
      const unsigned attr = (pk[m >> 3] >> ((m & 7) * 4)) & 15u;
      const float4 e = ld4(emb_ea + attr * EMB + c0);
      const int ok = OKv[m], ol = OLv[m];
      acc[ok].x = fmaf(X[ol].x, e.x, acc[ok].x);
      acc[ok].y = fmaf(X[ol].y, e.y, acc[ok].y);
      acc[ok].z = fmaf(X[ol].z, e.z, acc[ok].z);
      acc[ok].w = fmaf(X[ol].w, e.w, acc[ok].w);
    }
    // ---- hi/lo pack -> A-fragment LDS (row = (k>>2)*16 + q2*4 + (k&3)) ----
    #pragma unroll
    for (int k = 0; k < 8; ++k) {
      const unsigned h0 = cvt_pk_bf16(acc[k].x, acc[k].y);
      const unsigned h1 = cvt_pk_bf16(acc[k].z, acc[k].w);
      const float r0 = acc[k].x - __uint_as_float(h0 << 16);
      const float r1 = acc[k].y - __uint_as_float(h0 & 0xFFFF0000u);
      const float r2 = acc[k].z - __uint_as_float(h1 << 16);
      const float r3 = acc[k].w - __uint_as_float(h1 & 0xFFFF0000u);
      const int off = ((k >> 2) * 16 + q2 * 4 + (k & 3)) * 68 + (wv * 16 + m16) * 2;
      *(uint2*)(fragA + off) = make_uint2(h0, h1);
      *(uint2*)(fragA + 2176 + off) = make_uint2(cvt_pk_bf16(r0, r1),
                                                 cvt_pk_bf16(r2, r3));
    }
    __syncthreads();   // 2-wave scope

    // ---- MFMA: wave wv computes u = 4wv..4wv+3 for both M-tiles ----
    floatx4 C[4][2];
    #pragma unroll
    for (int ul = 0; ul < 4; ++ul)
      #pragma unroll
      for (int mt = 0; mt < 2; ++mt) C[ul][mt] = (floatx4){0.f, 0.f, 0.f, 0.f};

    #pragma unroll
    for (int kt = 0; kt < 4; ++kt) {
      const uint4* wp0 = wfrag + ((((l * 4 + kt) * 8 + wv * 4) * 2) << 6);
      FragU Bh[4], Bl[4];
      #pragma unroll
      for (int ul = 0; ul < 4; ++ul) {
        Bh[ul].q = wp0[ul * 128 + lane];
        Bl[ul].q = wp0[ul * 128 + 64 + lane];
      }
      #pragma unroll
      for (int mt = 0; mt < 2; ++mt) {
        const unsigned* fa = fragA + (mt * 16 + m16) * 68 + kt * 16 + q2 * 4;
        FragU Ah, Al;
        Ah.q = *(const uint4*)fa;
        Al.q = *(const uint4*)(fa + 2176);
        #pragma unroll
        for (int ul = 0; ul < 4; ++ul) {
          C[ul][mt] = __builtin_amdgcn_mfma_f32_16x16x32_bf16(Ah.v, Bh[ul].v, C[ul][mt], 0, 0, 0);
          C[ul][mt] = __builtin_amdgcn_mfma_f32_16x16x32_bf16(Al.v, Bh[ul].v, C[ul][mt], 0, 0, 0);
          C[ul][mt] = __builtin_amdgcn_mfma_f32_16x16x32_bf16(Ah.v, Bl[ul].v, C[ul][mt], 0, 0, 0);
        }
      }
    }
    __syncthreads();   // reads done before next layer overwrites fragA

    // ---- residual + relu in registers: C[ul][mt][r] = (pair q2, k=mt*4+r,
    //      channel c0+ul) — exactly this lane's X slots ----
    const float4 bc = ld4(b_conv + l * EMB + c0);
    #pragma unroll
    for (int mt = 0; mt < 2; ++mt)
      #pragma unroll
      for (int r = 0; r < 4; ++r) {
        const int k = mt * 4 + r;
        X[k].x += fmaxf(C[0][mt][r] + bc.x, 0.f);
        X[k].y += fmaxf(C[1][mt][r] + bc.y, 0.f);
        X[k].z += fmaxf(C[2][mt][r] + bc.z, 0.f);
        X[k].w += fmaxf(C[3][mt][r] + bc.w, 0.f);
      }
  }

  // ---- pooling: max over k (lane-local), dot w_pred, wave reduce, atomic ----
  float4 pv = X[0];
  #pragma unroll
  for (int k = 1; k < 8; ++k) {
    pv.x = fmaxf(pv.x, X[k].x);
    pv.y = fmaxf(pv.y, X[k].y);
    pv.z = fmaxf(pv.z, X[k].z);
    pv.w = fmaxf(pv.w, X[k].w);
  }
  const float4 wp = ld4(w_pred + c0);
  float s = pv.x * wp.x + pv.y * wp.y + pv.z * wp.z + pv.w * wp.w;
  #pragma unroll
  for (int off = 32; off; off >>= 1) s += __shfl_xor(s, off, 64);
  if (lane == 0) atomicAdd(out + g, s);   // 2 atomics/block (one per wave)
}

extern "C" void kernel_launch(void* const* d_in, const int* in_sizes, int n_in,
                              void* d_out, int out_size, void* d_ws, size_t ws_size,
                              hipStream_t stream) {
  const int*   x         = (const int*)d_in[0];
  const int*   edge_attr = (const int*)d_in[1];
  const int*   tuplefeat = (const int*)d_in[2];
  const float* emb_x     = (const float*)d_in[12];
  const float* emb_ea    = (const float*)d_in[13];
  const float* emb_tf    = (const float*)d_in[14];
  const float* w_ti      = (const float*)d_in[15];
  const float* b_ti      = (const float*)d_in[16];
  const float* w_conv    = (const float*)d_in[17];
  const float* b_conv    = (const float*)d_in[18];
  const float* w_pred    = (const float*)d_in[19];
  const float* b_pred    = (const float*)d_in[20];
  float* out = (float*)d_out;
  float* lin32 = (float*)d_ws;                               // 32*128 fp32 = 16 KB
  uint4* wfrag = (uint4*)((char*)d_ws + 32 * EMB * 4);       // 320 KB B-fragments

  hipLaunchKernelGGL(prep_kernel, dim3(73), dim3(512), 0, stream,
                     emb_x, w_ti, b_ti, w_conv, b_pred, lin32, wfrag, out);
  hipLaunchKernelGGL(i2gnn_mfma, dim3(8192), dim3(128), 0, stream,
                     x, edge_attr, tuplefeat, emb_x, emb_tf, emb_ea, lin32,
                     b_conv, w_pred, wfrag, out);
}

// Round 12
// 303.937 us; speedup vs baseline: 1.0154x; 1.0154x over previous
//
#include <hip/hip_runtime.h>
#include <hip/hip_bf16.h>

#define EMB 128

typedef __attribute__((ext_vector_type(8))) short short8;   // 8 bf16 (4 VGPRs)
typedef __attribute__((ext_vector_type(4))) float floatx4;  // MFMA C/D

// 26 valid (ok, di, ol) message combos: deltas = {1,2,-1,-2}, ol = ok+delta in [0,8)
static constexpr int OKv[26] = {0,0,1,1,1,2,2,2,2,3,3,3,3,4,4,4,4,5,5,5,5,6,6,6,7,7};
static constexpr int DIv[26] = {0,1,0,1,2,0,1,2,3,0,1,2,3,0,1,2,3,0,1,2,3,0,2,3,2,3};
static constexpr int OLv[26] = {1,2,2,3,0,3,4,1,0,4,5,2,1,5,6,3,2,6,7,4,3,7,5,4,6,5};

__device__ __forceinline__ float2 ld2(const float* p) { return *(const float2*)p; }

// round-to-nearest-even bf16 bits of x, kept in the TOP 16 bits (low 16 zero)
__device__ __forceinline__ unsigned bf16_rne_hi(float x) {
  unsigned u = __float_as_uint(x);
  return (u + 0x7FFFu + ((u >> 16) & 1u)) & 0xFFFF0000u;
}
__device__ __forceinline__ float bf16hi_f(float x) {
  return __uint_as_float(bf16_rne_hi(x));
}
// HW packed cvt: a -> low 16, b -> high 16 (v_cvt_pk_bf16_f32 on gfx950)
__device__ __forceinline__ unsigned cvt_pk_bf16(float a, float b) {
  __hip_bfloat162 h = __float22bfloat162_rn(make_float2(a, b));
  unsigned r; __builtin_memcpy(&r, &h, 4); return r;
}

union FragU { unsigned u[4]; uint4 q; short8 v; };

// LOGICAL CHANNEL PERMUTATION (R9-verified): MFMA C physical position
// (u, n=lane&15) carries logical channel L(u,n) = 2*((u>>1)*16 + n) + (u&1).
// Wave wv computes u in {2wv, 2wv+1} -> lane (wv, m16) holds the ADJACENT
// logical pair c0 = 2*(wv*16+m16), c0+1. Only wfrag bakes the permutation.

// Fused prep, grid 73 x 512 (R10: prep shape is total-time-neutral; the
// ~73 us total-minus-main gap is fixed harness overhead):
//  b 0..31  : lin32 row b (4-way f-split + LDS reduce)
//  b 32..71 : w_conv -> B-fragment hi/lo pre-pack with permuted N
//  b 72     : out[g] = b_pred[0]
__global__ __launch_bounds__(512) void prep_kernel(
    const float* __restrict__ emb_x,
    const float* __restrict__ w_ti,
    const float* __restrict__ b_ti,
    const float* __restrict__ w_conv,
    const float* __restrict__ b_pred,
    float* __restrict__ lin32,
    uint4* __restrict__ wfrag,
    float* __restrict__ out) {
  const int b = blockIdx.x, tid = threadIdx.x;
  if (b < 32) {
    __shared__ float red[4][EMB];
    const int e = tid & 127, fh = tid >> 7;      // fh in [0,4)
    const float* xr = emb_x + b * EMB;
    float s = 0.f;
    #pragma unroll 8
    for (int f = fh * 32; f < fh * 32 + 32; ++f)
      s = fmaf(xr[f], w_ti[f * EMB + e], s);
    red[fh][e] = s;
    __syncthreads();
    if (fh == 0)
      lin32[b * EMB + e] =
          b_ti[e] + ((red[0][e] + red[1][e]) + (red[2][e] + red[3][e]));
  } else if (b < 72) {
    const int id   = (b - 32) * 512 + tid;   // 320 frags * 64 lanes = 20480
    const int lane = id & 63;
    const int f    = id >> 6;
    const int pass = f & 1;           // 0 = hi, 1 = lo
    const int u    = (f >> 1) & 7;    // N-tile (physical)
    const int t    = (f >> 4) & 3;    // K-tile
    const int l    = f >> 6;          // layer
    const int q    = lane >> 4, n = lane & 15;
    const int cN   = 2 * ((u >> 1) * 16 + n) + (u & 1);   // logical out channel
    unsigned w[4] = {0u, 0u, 0u, 0u};
    #pragma unroll
    for (int j = 0; j < 8; ++j) {
      const int kk = t * 32 + q * 8 + j;    // logical in channel (canonical)
      float val = w_conv[l * (EMB * EMB) + kk * EMB + cN];
      if (pass) val = val - bf16hi_f(val);
      const unsigned bb = bf16_rne_hi(val);
      w[j >> 1] |= (j & 1) ? bb : (bb >> 16);
    }
    wfrag[id] = make_uint4(w[0], w[1], w[2], w[3]);
  } else {
    if (tid < 64) out[tid] = b_pred[0];
  }
}

// R9 structure (best: 228 us, 104 VGPR, zero spill) + ONE change: the four
// B-fragments for kt+1 are prefetched into a ping-pong register buffer while
// kt's 24 MFMAs execute — targets the suspected exposed L2 latency of the
// in-loop wfrag loads (320 KB table, not L1-resident at 4 blocks/CU).
// No occupancy attribute (R1/R6: forcing a budget -> 0.5-1.6 GB spills).
__global__ __launch_bounds__(256)
void i2gnn_mfma(
    const int* __restrict__ x,
    const int* __restrict__ edge_attr,
    const int* __restrict__ tuplefeat,
    const float* __restrict__ emb_x,
    const float* __restrict__ emb_tf,
    const float* __restrict__ emb_ea,
    const float* __restrict__ lin32,
    const float* __restrict__ b_conv,
    const float* __restrict__ w_pred,
    const uint4* __restrict__ wfrag,
    float* __restrict__ out)
{
  __shared__ __align__(16) unsigned fragA[2 * 64 * 68];   // 34816 B, lo at +4352

  const int tid = threadIdx.x;
  const int wv = tid >> 6, lane = tid & 63;
  const int m16 = lane & 15, q2 = lane >> 4;
  const int pc = wv * 16 + m16;        // logical pair-column this lane produces
  const int c0 = pc * 2;               // logical channels c0, c0+1

  const int i = blockIdx.x;
  const int ibase = i & ~63, io = i & 63;
  const int g = i >> 6;

  // 26 edge attrs (4 bits each) — function of i only
  unsigned pk[4] = {0u, 0u, 0u, 0u};
  #pragma unroll
  for (int m = 0; m < 26; ++m) {
    const int kg = ibase + ((io + OKv[m]) & 63);
    const unsigned a = (unsigned)edge_attr[(kg << 2) + DIv[m]];
    pk[m >> 3] |= a << ((m & 7) * 4);
  }

  // tupleinit in C-layout: X[v][mt][r]; pair ps = mt&1 (this lane: 2*q2+ps),
  // k = (mt>>1)*4 + r; channels c0+v (adjacent logical pair).
  const int xi = x[i];
  const float2 xe = ld2(emb_x + xi * EMB + c0);
  float2 lj[2];
  #pragma unroll
  for (int ps = 0; ps < 2; ++ps) {
    const int jn = ibase + ((io + 2 * q2 + ps) & 63);
    lj[ps] = ld2(lin32 + x[jn] * EMB + c0);
  }
  floatx4 X[2][4];
  #pragma unroll
  for (int mt = 0; mt < 4; ++mt) {
    const int ps = mt & 1, kb = (mt >> 1) * 4;
    const int t0 = (i * 8 + 2 * q2 + ps) << 3;
    #pragma unroll
    for (int r = 0; r < 4; ++r) {
      const int2 tf2 = *(const int2*)(tuplefeat + 2 * (t0 + kb + r));
      const int row = (c0 < 64) ? tf2.x : tf2.y;   // c0,c0+1 in same half
      const float2 tf = ld2(emb_tf + row * 64 + (c0 & 63));
      X[0][mt][r] = xe.x * lj[ps].x * tf.x;
      X[1][mt][r] = xe.y * lj[ps].y * tf.y;
    }
  }

  for (int l = 0; l < 5; ++l) {
    // ---- message pass, lane-local on logical channels c0, c0+1 ----
    float acc[2][2][8];   // [v][ps][k]
    #pragma unroll
    for (int v = 0; v < 2; ++v)
      #pragma unroll
      for (int ps = 0; ps < 2; ++ps)
        #pragma unroll
        for (int k = 0; k < 8; ++k) acc[v][ps][k] = 0.f;
    #pragma unroll
    for (int m = 0; m < 26; ++m) {
      const unsigned attr = (pk[m >> 3] >> ((m & 7) * 4)) & 15u;
      const float2 e = ld2(emb_ea + attr * EMB + c0);
      const int ok = OKv[m], ol = OLv[m];
      const int mtb = 2 * (ol >> 2), rl = ol & 3;   // compile-time consts
      acc[0][0][ok] = fmaf(X[0][mtb + 0][rl], e.x, acc[0][0][ok]);
      acc[0][1][ok] = fmaf(X[0][mtb + 1][rl], e.x, acc[0][1][ok]);
      acc[1][0][ok] = fmaf(X[1][mtb + 0][rl], e.y, acc[1][0][ok]);
      acc[1][1][ok] = fmaf(X[1][mtb + 1][rl], e.y, acc[1][1][ok]);
    }
    // ---- single hi/lo pack, written straight into A-fragment layout ----
    #pragma unroll
    for (int ps = 0; ps < 2; ++ps)
      #pragma unroll
      for (int k = 0; k < 8; ++k) {
        const float a0 = acc[0][ps][k], a1 = acc[1][ps][k];
        const unsigned hi = cvt_pk_bf16(a0, a1);
        const float r0 = a0 - __uint_as_float(hi << 16);
        const float r1 = a1 - __uint_as_float(hi & 0xFFFF0000u);
        const int row = (ps + 2 * (k >> 2)) * 16 + q2 * 4 + (k & 3);
        fragA[row * 68 + pc] = hi;
        fragA[4352 + row * 68 + pc] = cvt_pk_bf16(r0, r1);
      }
    __syncthreads();

    // ---- MFMA with ping-pong B prefetch: load kt+1 while computing kt ----
    floatx4 C[2][4];
    #pragma unroll
    for (int v = 0; v < 2; ++v)
      #pragma unroll
      for (int mt = 0; mt < 4; ++mt) C[v][mt] = (floatx4){0.f, 0.f, 0.f, 0.f};

    FragU Bb[2][4];   // [buf][B0h, B0l, B1h, B1l]
    {
      const uint4* wp0 = wfrag + ((((l * 4 + 0) * 8 + 2 * wv) * 2) << 6);
      Bb[0][0].q = wp0[lane];        Bb[0][1].q = wp0[64 + lane];
      Bb[0][2].q = wp0[128 + lane];  Bb[0][3].q = wp0[192 + lane];
    }
    #pragma unroll
    for (int kt = 0; kt < 4; ++kt) {
      const int cb = kt & 1;
      if (kt < 3) {
        const uint4* wpn = wfrag + ((((l * 4 + kt + 1) * 8 + 2 * wv) * 2) << 6);
        Bb[cb ^ 1][0].q = wpn[lane];        Bb[cb ^ 1][1].q = wpn[64 + lane];
        Bb[cb ^ 1][2].q = wpn[128 + lane];  Bb[cb ^ 1][3].q = wpn[192 + lane];
      }
      #pragma unroll
      for (int mt = 0; mt < 4; ++mt) {
        const unsigned* fa = fragA + (mt * 16 + m16) * 68 + kt * 16 + q2 * 4;
        FragU Ah, Al;
        Ah.q = *(const uint4*)fa;
        Al.q = *(const uint4*)(fa + 4352);
        C[0][mt] = __builtin_amdgcn_mfma_f32_16x16x32_bf16(Ah.v, Bb[cb][0].v, C[0][mt], 0, 0, 0);
        C[0][mt] = __builtin_amdgcn_mfma_f32_16x16x32_bf16(Al.v, Bb[cb][0].v, C[0][mt], 0, 0, 0);
        C[0][mt] = __builtin_amdgcn_mfma_f32_16x16x32_bf16(Ah.v, Bb[cb][1].v, C[0][mt], 0, 0, 0);
        C[1][mt] = __builtin_amdgcn_mfma_f32_16x16x32_bf16(Ah.v, Bb[cb][2].v, C[1][mt], 0, 0, 0);
        C[1][mt] = __builtin_amdgcn_mfma_f32_16x16x32_bf16(Al.v, Bb[cb][2].v, C[1][mt], 0, 0, 0);
        C[1][mt] = __builtin_amdgcn_mfma_f32_16x16x32_bf16(Ah.v, Bb[cb][3].v, C[1][mt], 0, 0, 0);
      }
    }
    __syncthreads();   // reads done before next layer overwrites fragA

    // ---- residual + relu in registers (lane's C entries are c0, c0+1) ----
    const float2 bc = ld2(b_conv + l * EMB + c0);
    #pragma unroll
    for (int mt = 0; mt < 4; ++mt)
      #pragma unroll
      for (int r = 0; r < 4; ++r) {
        X[0][mt][r] += fmaxf(C[0][mt][r] + bc.x, 0.f);
        X[1][mt][r] += fmaxf(C[1][mt][r] + bc.y, 0.f);
      }
  }

  // ---- pooling: max over k per (v, pair), dot w_pred, xor-reduce, atomic ----
  const float2 wp = ld2(w_pred + c0);
  float s = 0.f;
  #pragma unroll
  for (int v = 0; v < 2; ++v) {
    float p0 = -3.4e38f, p1 = -3.4e38f;
    #pragma unroll
    for (int r = 0; r < 4; ++r) {
      p0 = fmaxf(p0, fmaxf(X[v][0][r], X[v][2][r]));   // ps=0: mt 0,2
      p1 = fmaxf(p1, fmaxf(X[v][1][r], X[v][3][r]));   // ps=1: mt 1,3
    }
    s = fmaf(p0 + p1, v ? wp.y : wp.x, s);
  }
  #pragma unroll
  for (int off = 32; off; off >>= 1) s += __shfl_xor(s, off, 64);
  if (lane == 0) atomicAdd(out + g, s);
}

extern "C" void kernel_launch(void* const* d_in, const int* in_sizes, int n_in,
                              void* d_out, int out_size, void* d_ws, size_t ws_size,
                              hipStream_t stream) {
  const int*   x         = (const int*)d_in[0];
  const int*   edge_attr = (const int*)d_in[1];
  const int*   tuplefeat = (const int*)d_in[2];
  const float* emb_x     = (const float*)d_in[12];
  const float* emb_ea    = (const float*)d_in[13];
  const float* emb_tf    = (const float*)d_in[14];
  const float* w_ti      = (const float*)d_in[15];
  const float* b_ti      = (const float*)d_in[16];
  const float* w_conv    = (const float*)d_in[17];
  const float* b_conv    = (const float*)d_in[18];
  const float* w_pred    = (const float*)d_in[19];
  const float* b_pred    = (const float*)d_in[20];
  float* out = (float*)d_out;
  float* lin32 = (float*)d_ws;                               // 32*128 fp32 = 16 KB
  uint4* wfrag = (uint4*)((char*)d_ws + 32 * EMB * 4);       // 320 KB B-fragments

  hipLaunchKernelGGL(prep_kernel, dim3(73), dim3(512), 0, stream,
                     emb_x, w_ti, b_ti, w_conv, b_pred, lin32, wfrag, out);
  hipLaunchKernelGGL(i2gnn_mfma, dim3(4096), dim3(256), 0, stream,
                     x, edge_attr, tuplefeat, emb_x, emb_tf, emb_ea, lin32,
                     b_conv, w_pred, wfrag, out);
}

// Round 13
// 300.232 us; speedup vs baseline: 1.0279x; 1.0123x over previous
//
#include <hip/hip_runtime.h>
#include <hip/hip_bf16.h>

#define EMB 128

typedef __attribute__((ext_vector_type(8))) short short8;   // 8 bf16 (4 VGPRs)
typedef __attribute__((ext_vector_type(4))) float floatx4;  // MFMA C/D
typedef __attribute__((ext_vector_type(2))) float v2f;      // -> v_pk_fma_f32

// 26 valid (ok, di, ol) message combos: deltas = {1,2,-1,-2}, ol = ok+delta in [0,8)
static constexpr int OKv[26] = {0,0,1,1,1,2,2,2,2,3,3,3,3,4,4,4,4,5,5,5,5,6,6,6,7,7};
static constexpr int DIv[26] = {0,1,0,1,2,0,1,2,3,0,1,2,3,0,1,2,3,0,1,2,3,0,2,3,2,3};
static constexpr int OLv[26] = {1,2,2,3,0,3,4,1,0,4,5,2,1,5,6,3,2,6,7,4,3,7,5,4,6,5};

__device__ __forceinline__ v2f ldv2(const float* p) { return *(const v2f*)p; }

// round-to-nearest-even bf16 bits of x, kept in the TOP 16 bits (low 16 zero)
__device__ __forceinline__ unsigned bf16_rne_hi(float x) {
  unsigned u = __float_as_uint(x);
  return (u + 0x7FFFu + ((u >> 16) & 1u)) & 0xFFFF0000u;
}
__device__ __forceinline__ float bf16hi_f(float x) {
  return __uint_as_float(bf16_rne_hi(x));
}
// HW packed cvt: a -> low 16, b -> high 16 (v_cvt_pk_bf16_f32 on gfx950)
__device__ __forceinline__ unsigned cvt_pk_bf16(float a, float b) {
  __hip_bfloat162 h = __float22bfloat162_rn(make_float2(a, b));
  unsigned r; __builtin_memcpy(&r, &h, 4); return r;
}

union FragU { unsigned u[4]; uint4 q; short8 v; };

// LOGICAL CHANNEL PERMUTATION (R9-verified): MFMA C physical position
// (u, n=lane&15) carries logical channel L(u,n) = 2*((u>>1)*16 + n) + (u&1).
// Wave wv computes u in {2wv, 2wv+1} -> lane (wv, m16) holds the ADJACENT
// logical pair c0 = 2*(wv*16+m16), c0+1. Only wfrag bakes the permutation.

// Fused prep, grid 73 x 512 (R10: prep shape is total-time-neutral; the
// ~73 us total-minus-main gap is fixed harness overhead):
//  b 0..31  : lin32 row b (4-way f-split + LDS reduce)
//  b 32..71 : w_conv -> B-fragment hi/lo pre-pack with permuted N
//  b 72     : out[g] = b_pred[0]
__global__ __launch_bounds__(512) void prep_kernel(
    const float* __restrict__ emb_x,
    const float* __restrict__ w_ti,
    const float* __restrict__ b_ti,
    const float* __restrict__ w_conv,
    const float* __restrict__ b_pred,
    float* __restrict__ lin32,
    uint4* __restrict__ wfrag,
    float* __restrict__ out) {
  const int b = blockIdx.x, tid = threadIdx.x;
  if (b < 32) {
    __shared__ float red[4][EMB];
    const int e = tid & 127, fh = tid >> 7;      // fh in [0,4)
    const float* xr = emb_x + b * EMB;
    float s = 0.f;
    #pragma unroll 8
    for (int f = fh * 32; f < fh * 32 + 32; ++f)
      s = fmaf(xr[f], w_ti[f * EMB + e], s);
    red[fh][e] = s;
    __syncthreads();
    if (fh == 0)
      lin32[b * EMB + e] =
          b_ti[e] + ((red[0][e] + red[1][e]) + (red[2][e] + red[3][e]));
  } else if (b < 72) {
    const int id   = (b - 32) * 512 + tid;   // 320 frags * 64 lanes = 20480
    const int lane = id & 63;
    const int f    = id >> 6;
    const int pass = f & 1;           // 0 = hi, 1 = lo
    const int u    = (f >> 1) & 7;    // N-tile (physical)
    const int t    = (f >> 4) & 3;    // K-tile
    const int l    = f >> 6;          // layer
    const int q    = lane >> 4, n = lane & 15;
    const int cN   = 2 * ((u >> 1) * 16 + n) + (u & 1);   // logical out channel
    unsigned w[4] = {0u, 0u, 0u, 0u};
    #pragma unroll
    for (int j = 0; j < 8; ++j) {
      const int kk = t * 32 + q * 8 + j;    // logical in channel (canonical)
      float val = w_conv[l * (EMB * EMB) + kk * EMB + cN];
      if (pass) val = val - bf16hi_f(val);
      const unsigned bb = bf16_rne_hi(val);
      w[j >> 1] |= (j & 1) ? bb : (bb >> 16);
    }
    wfrag[id] = make_uint4(w[0], w[1], w[2], w[3]);
  } else {
    if (tid < 64) out[tid] = b_pred[0];
  }
}

// R9 structure (best: 228 us, zero spill) + PACKED FP32: message pass, hi/lo
// pack residuals, tupleinit and residual+relu all rewritten on v2f so the
// adjacent-channel pair lowers to v_pk_fma_f32 / v_pk_add_f32 etc. — halves
// the dominant VALU instruction stream (R12 showed VALU 35% vs MFMA 24%:
// the two issue pipes combined are the binding resource).
// No occupancy attribute (R1/R6: forcing a budget -> 0.5-1.6 GB spills).
__global__ __launch_bounds__(256)
void i2gnn_mfma(
    const int* __restrict__ x,
    const int* __restrict__ edge_attr,
    const int* __restrict__ tuplefeat,
    const float* __restrict__ emb_x,
    const float* __restrict__ emb_tf,
    const float* __restrict__ emb_ea,
    const float* __restrict__ lin32,
    const float* __restrict__ b_conv,
    const float* __restrict__ w_pred,
    const uint4* __restrict__ wfrag,
    float* __restrict__ out)
{
  __shared__ __align__(16) unsigned fragA[2 * 64 * 68];   // 34816 B, lo at +4352

  const int tid = threadIdx.x;
  const int wv = tid >> 6, lane = tid & 63;
  const int m16 = lane & 15, q2 = lane >> 4;
  const int pc = wv * 16 + m16;        // logical pair-column this lane produces
  const int c0 = pc * 2;               // logical channels c0, c0+1

  const int i = blockIdx.x;
  const int ibase = i & ~63, io = i & 63;
  const int g = i >> 6;

  // 26 edge attrs (4 bits each) — function of i only
  unsigned pk[4] = {0u, 0u, 0u, 0u};
  #pragma unroll
  for (int m = 0; m < 26; ++m) {
    const int kg = ibase + ((io + OKv[m]) & 63);
    const unsigned a = (unsigned)edge_attr[(kg << 2) + DIv[m]];
    pk[m >> 3] |= a << ((m & 7) * 4);
  }

  // tupleinit in C-layout (packed): X2[mt][r] = v2f over channels (c0, c0+1);
  // pair ps = mt&1 (this lane: 2*q2+ps), k = (mt>>1)*4 + r.
  const int xi = x[i];
  const v2f xe = ldv2(emb_x + xi * EMB + c0);
  v2f lj[2];
  #pragma unroll
  for (int ps = 0; ps < 2; ++ps) {
    const int jn = ibase + ((io + 2 * q2 + ps) & 63);
    lj[ps] = ldv2(lin32 + x[jn] * EMB + c0);
  }
  v2f X2[4][4];   // [mt][r]
  #pragma unroll
  for (int mt = 0; mt < 4; ++mt) {
    const int ps = mt & 1, kb = (mt >> 1) * 4;
    const int t0 = (i * 8 + 2 * q2 + ps) << 3;
    const v2f xl = xe * lj[ps];
    #pragma unroll
    for (int r = 0; r < 4; ++r) {
      const int2 tf2 = *(const int2*)(tuplefeat + 2 * (t0 + kb + r));
      const int row = (c0 < 64) ? tf2.x : tf2.y;   // c0,c0+1 in same half
      const v2f tf = ldv2(emb_tf + row * 64 + (c0 & 63));
      X2[mt][r] = xl * tf;
    }
  }

  for (int l = 0; l < 5; ++l) {
    // ---- message pass, packed fp32 over (c0, c0+1) ----
    v2f acc[2][8];   // [ps][k]
    #pragma unroll
    for (int ps = 0; ps < 2; ++ps)
      #pragma unroll
      for (int k = 0; k < 8; ++k) acc[ps][k] = (v2f){0.f, 0.f};
    #pragma unroll
    for (int m = 0; m < 26; ++m) {
      const unsigned attr = (pk[m >> 3] >> ((m & 7) * 4)) & 15u;
      const v2f e = ldv2(emb_ea + attr * EMB + c0);
      const int ok = OKv[m], ol = OLv[m];
      const int mtb = 2 * (ol >> 2), rl = ol & 3;   // compile-time consts
      acc[0][ok] += X2[mtb + 0][rl] * e;            // v_pk_fma_f32
      acc[1][ok] += X2[mtb + 1][rl] * e;
    }
    // ---- single hi/lo pack (packed residual), straight into A-frag LDS ----
    #pragma unroll
    for (int ps = 0; ps < 2; ++ps)
      #pragma unroll
      for (int k = 0; k < 8; ++k) {
        const v2f a = acc[ps][k];
        const unsigned hi = cvt_pk_bf16(a.x, a.y);
        v2f hf; hf.x = __uint_as_float(hi << 16);
                hf.y = __uint_as_float(hi & 0xFFFF0000u);
        const v2f r = a - hf;                        // v_pk_add_f32
        const int row = (ps + 2 * (k >> 2)) * 16 + q2 * 4 + (k & 3);
        fragA[row * 68 + pc] = hi;
        fragA[4352 + row * 68 + pc] = cvt_pk_bf16(r.x, r.y);
      }
    __syncthreads();

    // ---- MFMA: wave computes u = {2wv, 2wv+1} for all 4 M-tiles ----
    floatx4 C[2][4];
    #pragma unroll
    for (int v = 0; v < 2; ++v)
      #pragma unroll
      for (int mt = 0; mt < 4; ++mt) C[v][mt] = (floatx4){0.f, 0.f, 0.f, 0.f};

    #pragma unroll
    for (int kt = 0; kt < 4; ++kt) {
      const uint4* wp0 = wfrag + ((((l * 4 + kt) * 8 + 2 * wv) * 2) << 6);
      FragU B0h, B0l, B1h, B1l;
      B0h.q = wp0[lane];        B0l.q = wp0[64 + lane];
      B1h.q = wp0[128 + lane];  B1l.q = wp0[192 + lane];
      #pragma unroll
      for (int mt = 0; mt < 4; ++mt) {
        const unsigned* fa = fragA + (mt * 16 + m16) * 68 + kt * 16 + q2 * 4;
        FragU Ah, Al;
        Ah.q = *(const uint4*)fa;
        Al.q = *(const uint4*)(fa + 4352);
        C[0][mt] = __builtin_amdgcn_mfma_f32_16x16x32_bf16(Ah.v, B0h.v, C[0][mt], 0, 0, 0);
        C[0][mt] = __builtin_amdgcn_mfma_f32_16x16x32_bf16(Al.v, B0h.v, C[0][mt], 0, 0, 0);
        C[0][mt] = __builtin_amdgcn_mfma_f32_16x16x32_bf16(Ah.v, B0l.v, C[0][mt], 0, 0, 0);
        C[1][mt] = __builtin_amdgcn_mfma_f32_16x16x32_bf16(Ah.v, B1h.v, C[1][mt], 0, 0, 0);
        C[1][mt] = __builtin_amdgcn_mfma_f32_16x16x32_bf16(Al.v, B1h.v, C[1][mt], 0, 0, 0);
        C[1][mt] = __builtin_amdgcn_mfma_f32_16x16x32_bf16(Ah.v, B1l.v, C[1][mt], 0, 0, 0);
      }
    }
    __syncthreads();   // reads done before next layer overwrites fragA

    // ---- residual + relu, packed: combine C[0]/C[1] into v2f lanes ----
    const v2f bc = ldv2(b_conv + l * EMB + c0);
    #pragma unroll
    for (int mt = 0; mt < 4; ++mt)
      #pragma unroll
      for (int r = 0; r < 4; ++r) {
        v2f o; o.x = C[0][mt][r]; o.y = C[1][mt][r];
        o += bc;                                     // v_pk_add_f32
        o.x = fmaxf(o.x, 0.f); o.y = fmaxf(o.y, 0.f);  // v_pk_max_f32
        X2[mt][r] += o;
      }
  }

  // ---- pooling: max over k per (v, pair), dot w_pred, xor-reduce, atomic ----
  const v2f wp = ldv2(w_pred + c0);
  v2f p0 = (v2f){-3.4e38f, -3.4e38f}, p1 = p0;
  #pragma unroll
  for (int r = 0; r < 4; ++r) {
    p0.x = fmaxf(p0.x, fmaxf(X2[0][r].x, X2[2][r].x));
    p0.y = fmaxf(p0.y, fmaxf(X2[0][r].y, X2[2][r].y));
    p1.x = fmaxf(p1.x, fmaxf(X2[1][r].x, X2[3][r].x));
    p1.y = fmaxf(p1.y, fmaxf(X2[1][r].y, X2[3][r].y));
  }
  const v2f ps = (p0 + p1) * wp;
  float s = ps.x + ps.y;
  #pragma unroll
  for (int off = 32; off; off >>= 1) s += __shfl_xor(s, off, 64);
  if (lane == 0) atomicAdd(out + g, s);
}

extern "C" void kernel_launch(void* const* d_in, const int* in_sizes, int n_in,
                              void* d_out, int out_size, void* d_ws, size_t ws_size,
                              hipStream_t stream) {
  const int*   x         = (const int*)d_in[0];
  const int*   edge_attr = (const int*)d_in[1];
  const int*   tuplefeat = (const int*)d_in[2];
  const float* emb_x     = (const float*)d_in[12];
  const float* emb_ea    = (const float*)d_in[13];
  const float* emb_tf    = (const float*)d_in[14];
  const float* w_ti      = (const float*)d_in[15];
  const float* b_ti      = (const float*)d_in[16];
  const float* w_conv    = (const float*)d_in[17];
  const float* b_conv    = (const float*)d_in[18];
  const float* w_pred    = (const float*)d_in[19];
  const float* b_pred    = (const float*)d_in[20];
  float* out = (float*)d_out;
  float* lin32 = (float*)d_ws;                               // 32*128 fp32 = 16 KB
  uint4* wfrag = (uint4*)((char*)d_ws + 32 * EMB * 4);       // 320 KB B-fragments

  hipLaunchKernelGGL(prep_kernel, dim3(73), dim3(512), 0, stream,
                     emb_x, w_ti, b_ti, w_conv, b_pred, lin32, wfrag, out);
  hipLaunchKernelGGL(i2gnn_mfma, dim3(4096), dim3(256), 0, stream,
                     x, edge_attr, tuplefeat, emb_x, emb_tf, emb_ea, lin32,
                     b_conv, w_pred, wfrag, out);
}